// Round 4
// baseline (301.047 us; speedup 1.0000x reference)
//
#include <hip/hip_runtime.h>
#include <math.h>

// Problem constants (B=2, N=512, C=64, H=8)
constexpr int BDIM = 1024;   // 16 waves: waves 0-7 -> bm0, waves 8-15 -> bm1
constexpr int NDIM = 512;
constexpr int CDIM = 64;
constexpr int HDIM = 8;

// R4: occupancy experiment. Per-thread math is byte-identical to R3 (thread
// owns one row n of one (b,m): 16+16 float4 loads, SGPR-resident W FMA chain,
// wave butterfly + LDS cross-wave reduce). NEW: 1024-thread blocks cover TWO
// (b,m) tiles each (half = t>>9 is wave-uniform), grid = 512 blocks = exactly
// 2 blocks/CU -> 32 waves/CU co-resident (vs 16-19 in R0/R2/R3, which all
// plateaued at ~110us / ~2.7 TB/s delivered). Aggregate MLP = waves x
// (compiler-pinned ~6-8 outstanding/wave); waves is the only movable factor.
// __launch_bounds__(1024, 8): 8 waves/EU -> 2 blocks/CU, VGPR cap 64 (R3
// measured 40 for the same per-thread body -> fits).
__global__ __launch_bounds__(BDIM, 8)
void mha_kernel(const float* __restrict__ q,
                const float* __restrict__ kk,
                const float* __restrict__ mask,
                const float* __restrict__ W,      // (H, 2C) row-major
                const float* __restrict__ bias,   // (H,)
                float* __restrict__ out)          // (B, N, N, H)
{
    __shared__ float red[2][8][HDIM];     // [half][wave-in-half][h]
    __shared__ float rsum_lds[2][HDIM];

    const int t    = threadIdx.x;
    const int half = t >> 9;              // wave-uniform (waves 0-7: 0, 8-15: 1)
    const int n    = t & 511;             // row within the (b,m) tile
    const int bm   = blockIdx.x * 2 + half;

    const float4* qp = (const float4*)(q  + (size_t)bm * NDIM * CDIM + (size_t)n * CDIM);
    const float4* kp = (const float4*)(kk + (size_t)bm * NDIM * CDIM + (size_t)n * CDIM);

    float4 xq[16];
    float4 xk[16];
#pragma unroll
    for (int j = 0; j < 16; ++j) xq[j] = qp[j];
#pragma unroll
    for (int j = 0; j < 16; ++j) xk[j] = kp[j];
    const float mval = mask[bm * NDIM + n];

    float acc[HDIM];
#pragma unroll
    for (int h = 0; h < HDIM; ++h) acc[h] = 0.0f;

#pragma unroll
    for (int h = 0; h < HDIM; ++h) {
        const float* wq = W + h * 2 * CDIM;      // uniform -> s_load
        float a = acc[h];
#pragma unroll
        for (int j = 0; j < 16; ++j) {
            a = fmaf(xq[j].x, wq[4 * j + 0], a);
            a = fmaf(xq[j].y, wq[4 * j + 1], a);
            a = fmaf(xq[j].z, wq[4 * j + 2], a);
            a = fmaf(xq[j].w, wq[4 * j + 3], a);
        }
        acc[h] = a;
    }
#pragma unroll
    for (int h = 0; h < HDIM; ++h) {
        const float* wk = W + h * 2 * CDIM + CDIM;
        float a = acc[h];
#pragma unroll
        for (int j = 0; j < 16; ++j) {
            a = fmaf(xk[j].x, wk[4 * j + 0], a);
            a = fmaf(xk[j].y, wk[4 * j + 1], a);
            a = fmaf(xk[j].z, wk[4 * j + 2], a);
            a = fmaf(xk[j].w, wk[4 * j + 3], a);
        }
        acc[h] = a;
    }

    float val[HDIM];
    float psum[HDIM];
#pragma unroll
    for (int h = 0; h < HDIM; ++h) {
        float v = __expf(acc[h] + bias[h]) * mval;
        val[h]  = v;
        psum[h] = v;
    }

    // sum over n (axis=2) within this half: wave butterfly, then cross-wave LDS
#pragma unroll
    for (int h = 0; h < HDIM; ++h) {
        float s = psum[h];
#pragma unroll
        for (int off = 32; off >= 1; off >>= 1)
            s += __shfl_xor(s, off, 64);
        psum[h] = s;
    }
    const int lane = t & 63;
    const int widh = (t >> 6) & 7;        // wave index within the half
    if (lane == 0) {
#pragma unroll
        for (int h = 0; h < HDIM; ++h) red[half][widh][h] = psum[h];
    }
    __syncthreads();
    if (n < HDIM) {
        float s = 0.0f;
#pragma unroll
        for (int w = 0; w < 8; ++w) s += red[half][w][n];
        rsum_lds[half][n] = 1.0f / s;
    }
    __syncthreads();

    float rs[HDIM];
#pragma unroll
    for (int h = 0; h < HDIM; ++h) rs[h] = rsum_lds[half][h];

    float* orow = out + (size_t)bm * NDIM * HDIM;
    float4 lo = make_float4(val[0] * rs[0], val[1] * rs[1],
                            val[2] * rs[2], val[3] * rs[3]);
    float4 hi = make_float4(val[4] * rs[4], val[5] * rs[5],
                            val[6] * rs[6], val[7] * rs[7]);
    float4* op = (float4*)(orow + (size_t)n * HDIM);
    op[0] = lo;
    op[1] = hi;
}

extern "C" void kernel_launch(void* const* d_in, const int* in_sizes, int n_in,
                              void* d_out, int out_size, void* d_ws, size_t ws_size,
                              hipStream_t stream) {
    const float* q    = (const float*)d_in[0];
    const float* k    = (const float*)d_in[1];
    const float* mask = (const float*)d_in[2];
    const float* W    = (const float*)d_in[3];
    const float* b    = (const float*)d_in[4];
    float* out = (float*)d_out;

    hipLaunchKernelGGL(mha_kernel, dim3(NDIM), dim3(BDIM), 0, stream,
                       q, k, mask, W, b, out);
}